// Round 1
// baseline (269.868 us; speedup 1.0000x reference)
//
#include <hip/hip_runtime.h>

// Problem constants (from reference setup_inputs)
constexpr int B  = 8;
constexpr int C  = 256;
constexpr int HW = 128 * 128;     // 16384 pixels per plane
constexpr int K  = 64;            // selected channels
#define SMOOTH 1e-6f

__device__ __forceinline__ float uncert(float v) {
    float s = 1.0f / (1.0f + expf(-v));
    return -s * logf(s + SMOOTH);
}

// Kernel 1: score[b,c] = mean over plane of -sigmoid(x)*log(sigmoid(x)+eps)
// One block (256 threads) per (b,c) plane of 16384 floats = 4096 float4.
__global__ void score_kernel(const float* __restrict__ x, float* __restrict__ score) {
    const int plane = blockIdx.x;                       // b*C + c
    const float4* xp = (const float4*)(x + (size_t)plane * HW);
    const int t = threadIdx.x;

    float acc = 0.0f;
#pragma unroll
    for (int i = 0; i < 16; ++i) {
        float4 v = xp[t + i * 256];
        acc += uncert(v.x) + uncert(v.y) + uncert(v.z) + uncert(v.w);
    }
    // wave (64-lane) reduce
#pragma unroll
    for (int off = 32; off > 0; off >>= 1) acc += __shfl_down(acc, off, 64);

    __shared__ float smem[4];
    if ((t & 63) == 0) smem[t >> 6] = acc;
    __syncthreads();
    if (t == 0) score[plane] = (smem[0] + smem[1] + smem[2] + smem[3]) * (1.0f / HW);
}

// Kernel 2: per batch, exact rank of each channel by ascending score with
// lax.top_k tie-break (lower index first). sel[b][rank] = channel, rank < K.
__global__ void topk_kernel(const float* __restrict__ score, int* __restrict__ sel) {
    const int b = blockIdx.x;
    const int t = threadIdx.x;                          // channel, 0..255
    __shared__ float sc[C];
    sc[t] = score[b * C + t];
    __syncthreads();

    const float my = sc[t];
    int rank = 0;
#pragma unroll 8
    for (int j = 0; j < C; ++j) {
        float o = sc[j];
        rank += (o < my) || (o == my && j < t);
    }
    if (rank < K) sel[b * K + rank] = t;
}

// Kernel 3: attn[b,p] = sigmoid(bias + sum_k w[k] * x[b, sel[b][k], p])
// 16 blocks per batch; each thread handles one float4 (4 pixels).
__global__ void attn_kernel(const float* __restrict__ x, const int* __restrict__ sel,
                            const float* __restrict__ w, const float* __restrict__ bias,
                            float* __restrict__ attn) {
    const int b     = blockIdx.x >> 4;
    const int chunk = blockIdx.x & 15;
    const int t     = threadIdx.x;

    __shared__ float ws[K];
    __shared__ int   chs[K];
    if (t < K) { ws[t] = w[t]; chs[t] = sel[b * K + t]; }
    __syncthreads();

    const int p4 = chunk * 256 + t;                     // float4 idx in plane [0,4096)
    const float4* xb = (const float4*)(x + (size_t)b * C * HW);

    float ax = 0.f, ay = 0.f, az = 0.f, aw = 0.f;
#pragma unroll 8
    for (int k = 0; k < K; ++k) {
        float4 v = xb[(size_t)chs[k] * (HW / 4) + p4];
        float wk = ws[k];
        ax += wk * v.x; ay += wk * v.y; az += wk * v.z; aw += wk * v.w;
    }
    const float b0 = bias[0];
    float4 o;
    o.x = 1.0f / (1.0f + expf(-(ax + b0)));
    o.y = 1.0f / (1.0f + expf(-(ay + b0)));
    o.z = 1.0f / (1.0f + expf(-(az + b0)));
    o.w = 1.0f / (1.0f + expf(-(aw + b0)));
    ((float4*)attn)[((size_t)b << 12) + p4] = o;
}

// Kernel 4: out[b,c,p] = x[b,c,p] * attn[b,p]   (float4 per thread)
__global__ void mul_kernel(const float* __restrict__ x, const float* __restrict__ attn,
                           float* __restrict__ out) {
    const size_t i = (size_t)blockIdx.x * blockDim.x + threadIdx.x;  // float4 idx, 2^23 total
    const float4* x4 = (const float4*)x;
    const float4* a4 = (const float4*)attn;
    float4 v = x4[i];
    // per-batch float4 count = C*HW/4 = 2^20; per-plane = 2^12
    float4 a = a4[((i >> 20) << 12) | (i & 4095)];
    float4 o; o.x = v.x * a.x; o.y = v.y * a.y; o.z = v.z * a.z; o.w = v.w * a.w;
    ((float4*)out)[i] = o;
}

extern "C" void kernel_launch(void* const* d_in, const int* in_sizes, int n_in,
                              void* d_out, int out_size, void* d_ws, size_t ws_size,
                              hipStream_t stream) {
    const float* x    = (const float*)d_in[0];
    const float* w    = (const float*)d_in[1];
    const float* bias = (const float*)d_in[2];
    float* out = (float*)d_out;

    char* ws = (char*)d_ws;
    float* score = (float*)ws;                 // 2048 floats  = 8 KiB
    int*   sel   = (int*)(ws + 8192);          // 512 ints     = 2 KiB
    float* attn  = (float*)(ws + 16384);       // B*HW floats  = 512 KiB

    score_kernel<<<B * C, 256, 0, stream>>>(x, score);
    topk_kernel<<<B, C, 0, stream>>>(score, sel);
    attn_kernel<<<B * 16, 256, 0, stream>>>(x, sel, w, bias, attn);
    const int n4 = B * C * HW / 4;             // 8388608 float4
    mul_kernel<<<n4 / 256, 256, 0, stream>>>(x, attn, out);
}